// Round 1
// baseline (69.107 us; speedup 1.0000x reference)
//
#include <hip/hip_runtime.h>

// DecoupledMoE: out[b,o,p] = sum_i (W_shared[o,i] + w[b]*W_routed[e_b,o,i]) * x[b,i,p]
//                            + (b_shared[o] + w[b]*b_routed[e_b,o])
// B=128, C_IN=C_OUT=64, HW=3136. Memory-bound (206 MB min traffic, 16 FLOP/B).

#define HW    3136
#define CIN   64
#define COUT  64
#define CHUNK 512   // pixels per block
#define TP    8     // pixels per lane (contiguous)
#define OT    16    // output channels per wave (4 waves * 16 = 64)

__global__ __launch_bounds__(256, 2) void moe_fused(
    const float* __restrict__ x,
    const float* __restrict__ weights,
    const int*   __restrict__ indices,
    const float* __restrict__ W_shared,
    const float* __restrict__ b_shared,
    const float* __restrict__ W_routed,
    const float* __restrict__ b_routed,
    float* __restrict__ out)
{
    __shared__ float Wl[COUT][CIN];   // fused per-sample weight, 16 KB
    __shared__ float bl[COUT];

    const int b  = blockIdx.y;
    const float wb = weights[b];
    const int e  = indices[b];

    // Stage fused weight into LDS (one-time per block; W arrays are L2-resident)
    const float* __restrict__ Wr = W_routed + (size_t)e * (COUT * CIN);
    for (int t = threadIdx.x; t < COUT * CIN; t += 256)
        Wl[t >> 6][t & 63] = W_shared[t] + wb * Wr[t];
    if (threadIdx.x < COUT)
        bl[threadIdx.x] = b_shared[threadIdx.x] + wb * b_routed[e * COUT + threadIdx.x];
    __syncthreads();

    const int wave = threadIdx.x >> 6;
    const int lane = threadIdx.x & 63;

    int c0 = blockIdx.x * CHUNK;
    if (c0 > HW - CHUNK) c0 = HW - CHUNK;   // last chunk overlaps; same values rewritten
    const int p0 = c0 + lane * TP;
    const int ob = wave * OT;

    const float* __restrict__ xb = x + (size_t)b * CIN * HW + p0;

    float acc[OT][TP];
    #pragma unroll
    for (int o = 0; o < OT; ++o)
        #pragma unroll
        for (int p = 0; p < TP; ++p) acc[o][p] = 0.f;

    // K loop over input channels in blocks of 4
    for (int ib = 0; ib < CIN / 4; ++ib) {
        float4 xv[4][2];
        #pragma unroll
        for (int di = 0; di < 4; ++di) {
            const float* xp = xb + (size_t)(ib * 4 + di) * HW;
            xv[di][0] = *(const float4*)(xp);
            xv[di][1] = *(const float4*)(xp + 4);
        }
        #pragma unroll
        for (int o = 0; o < OT; ++o) {
            // wave-uniform broadcast read, conflict-free
            const float4 wv = *(const float4*)&Wl[ob + o][ib * 4];
            #pragma unroll
            for (int di = 0; di < 4; ++di) {
                const float w = (&wv.x)[di];
                acc[o][0] += w * xv[di][0].x;
                acc[o][1] += w * xv[di][0].y;
                acc[o][2] += w * xv[di][0].z;
                acc[o][3] += w * xv[di][0].w;
                acc[o][4] += w * xv[di][1].x;
                acc[o][5] += w * xv[di][1].y;
                acc[o][6] += w * xv[di][1].z;
                acc[o][7] += w * xv[di][1].w;
            }
        }
    }

    // Epilogue: add fused bias, coalesced float4 stores
    float* __restrict__ op_base = out + (size_t)b * COUT * HW + p0;
    #pragma unroll
    for (int o = 0; o < OT; ++o) {
        const float be = bl[ob + o];
        float* op = op_base + (size_t)(ob + o) * HW;
        float4 r0 = make_float4(acc[o][0] + be, acc[o][1] + be,
                                acc[o][2] + be, acc[o][3] + be);
        float4 r1 = make_float4(acc[o][4] + be, acc[o][5] + be,
                                acc[o][6] + be, acc[o][7] + be);
        *(float4*)(op)     = r0;
        *(float4*)(op + 4) = r1;
    }
}

extern "C" void kernel_launch(void* const* d_in, const int* in_sizes, int n_in,
                              void* d_out, int out_size, void* d_ws, size_t ws_size,
                              hipStream_t stream) {
    const float* x        = (const float*)d_in[0];
    const float* weights  = (const float*)d_in[1];
    const int*   indices  = (const int*)  d_in[2];
    const float* W_shared = (const float*)d_in[3];
    const float* b_shared = (const float*)d_in[4];
    const float* W_routed = (const float*)d_in[5];
    const float* b_routed = (const float*)d_in[6];
    float* out = (float*)d_out;

    dim3 grid(7, 128);   // 7 pixel-chunks (last overlaps) x 128 samples
    moe_fused<<<grid, 256, 0, stream>>>(x, weights, indices,
                                        W_shared, b_shared, W_routed, b_routed, out);
}

// Round 2
// 62.743 us; speedup vs baseline: 1.1014x; 1.1014x over previous
//
#include <hip/hip_runtime.h>

// DecoupledMoE: out[b,o,p] = sum_i (W_shared[o,i] + w[b]*W_routed[e_b,o,i]) * x[b,i,p]
//                            + (b_shared[o] + w[b]*b_routed[e_b,o])
// B=128, C_IN=C_OUT=64, HW=3136 (fp32). Latency-bound last round (VALU 34%, occ 15%):
// acc[16][8] blew the 128-VGPR tier. This round: OT=8 -> acc=64 VGPR, whole wave
// state ~112 VGPR -> 4 waves/SIMD; block = 32 out-channels; grid 1792.

#define HW     3136
#define CIN    64
#define COUT   64
#define CHUNK  512   // pixels per block (128 float4)
#define OT     8     // output channels per wave (4 waves * 8 = 32 per block)
#define GSIZE  32    // output channels per block

__global__ __launch_bounds__(256, 4) void moe_fused(
    const float* __restrict__ x,
    const float* __restrict__ weights,
    const int*   __restrict__ indices,
    const float* __restrict__ W_shared,
    const float* __restrict__ b_shared,
    const float* __restrict__ W_routed,
    const float* __restrict__ b_routed,
    float* __restrict__ out)
{
    __shared__ float Wl[GSIZE * CIN];   // fused per-sample weight slice, 8 KB
    __shared__ float bl[GSIZE];

    // bid = [pair_hi | g | xcd3]: the two blocks sharing an x-chunk (g=0/1) are
    // 8 apart -> same XCD under %8 round-robin, dispatched adjacently (L2 reuse).
    const int bid = blockIdx.x;
    const int g   = (bid >> 3) & 1;
    const int cid = ((bid >> 4) << 3) | (bid & 7);   // [0, 896)
    const int b   = cid & 127;                       // sample
    int c0 = (cid >> 7) * CHUNK;                     // chunk 0..6
    if (c0 > HW - CHUNK) c0 = HW - CHUNK;            // last chunk overlaps (same values)

    const float wb = weights[b];
    const int   e  = indices[b];
    const int   G  = g * GSIZE;

    // Stage fused weight slice into LDS (coalesced, once per block)
    const float* __restrict__ Wsp = W_shared + G * CIN;
    const float* __restrict__ Wrp = W_routed + (size_t)e * (COUT * CIN) + G * CIN;
    #pragma unroll
    for (int k = 0; k < 8; ++k) {
        const int idx = threadIdx.x + k * 256;
        Wl[idx] = Wsp[idx] + wb * Wrp[idx];
    }
    if (threadIdx.x < GSIZE)
        bl[threadIdx.x] = b_shared[G + threadIdx.x]
                        + wb * b_routed[e * COUT + G + threadIdx.x];
    __syncthreads();

    const int wave = threadIdx.x >> 6;
    const int lane = threadIdx.x & 63;
    const int ob   = wave * OT;   // row within block's 32-channel group

    // lane covers float4 #lane and #(lane+64) of the 128-float4 chunk:
    // both loads/stores are fully dense 1KB/wave-instruction.
    const float* __restrict__ xb = x + (size_t)b * CIN * HW + c0 + 4 * lane;

    float acc[OT][8];
    #pragma unroll
    for (int o = 0; o < OT; ++o)
        #pragma unroll
        for (int p = 0; p < 8; ++p) acc[o][p] = 0.f;

    for (int ib = 0; ib < CIN / 4; ++ib) {
        float4 xv0[4], xv1[4];
        #pragma unroll
        for (int di = 0; di < 4; ++di) {
            const float* xp = xb + (size_t)(ib * 4 + di) * HW;
            xv0[di] = *(const float4*)(xp);
            xv1[di] = *(const float4*)(xp + 256);
        }
        #pragma unroll
        for (int o = 0; o < OT; ++o) {
            // wave-uniform broadcast read (conflict-free), 1 read per 32 FMAs
            const float4 wv = *(const float4*)&Wl[(ob + o) * CIN + ib * 4];
            #pragma unroll
            for (int di = 0; di < 4; ++di) {
                const float w = (&wv.x)[di];
                acc[o][0] += w * xv0[di].x;
                acc[o][1] += w * xv0[di].y;
                acc[o][2] += w * xv0[di].z;
                acc[o][3] += w * xv0[di].w;
                acc[o][4] += w * xv1[di].x;
                acc[o][5] += w * xv1[di].y;
                acc[o][6] += w * xv1[di].z;
                acc[o][7] += w * xv1[di].w;
            }
        }
    }

    // Epilogue: fused bias, dense float4 stores
    float* __restrict__ op_base = out + (size_t)b * COUT * HW + c0 + 4 * lane;
    #pragma unroll
    for (int o = 0; o < OT; ++o) {
        const float be = bl[ob + o];
        float* op = op_base + (size_t)(G + ob + o) * HW;
        float4 r0 = make_float4(acc[o][0] + be, acc[o][1] + be,
                                acc[o][2] + be, acc[o][3] + be);
        float4 r1 = make_float4(acc[o][4] + be, acc[o][5] + be,
                                acc[o][6] + be, acc[o][7] + be);
        *(float4*)(op)       = r0;
        *(float4*)(op + 256) = r1;
    }
}

extern "C" void kernel_launch(void* const* d_in, const int* in_sizes, int n_in,
                              void* d_out, int out_size, void* d_ws, size_t ws_size,
                              hipStream_t stream) {
    const float* x        = (const float*)d_in[0];
    const float* weights  = (const float*)d_in[1];
    const int*   indices  = (const int*)  d_in[2];
    const float* W_shared = (const float*)d_in[3];
    const float* b_shared = (const float*)d_in[4];
    const float* W_routed = (const float*)d_in[5];
    const float* b_routed = (const float*)d_in[6];
    float* out = (float*)d_out;

    // 7 chunks x 128 samples x 2 channel-groups = 1792 blocks (7 per CU)
    moe_fused<<<dim3(1792), 256, 0, stream>>>(x, weights, indices,
                                              W_shared, b_shared, W_routed, b_routed, out);
}